// Round 1
// baseline (344.808 us; speedup 1.0000x reference)
//
#include <hip/hip_runtime.h>
#include <hip/hip_bf16.h>
#include <math.h>

#define T_TOK 4096
#define DIM   1024
#define NEXP  8
#define DHID  4096
#define NDOUT 1024
#define BM    128
#define BN    128
#define BK    64
#define MAXTILES 40   // T/BM + NEXP worst case

typedef short bf16x8 __attribute__((ext_vector_type(8)));
typedef float f32x4 __attribute__((ext_vector_type(4)));

__device__ __forceinline__ unsigned short f2bf(float f) {
  unsigned u = __float_as_uint(f);
  u += 0x7fffu + ((u >> 16) & 1u);        // RNE
  return (unsigned short)(u >> 16);
}
__device__ __forceinline__ unsigned pack2bf(float a, float b) {
  return (unsigned)f2bf(a) | ((unsigned)f2bf(b) << 16);
}
// byte offset into a [128 rows][128 bytes] LDS tile, T2 XOR swizzle
__device__ __forceinline__ int swz(int row, int kbyte) {
  return ((row << 7) + kbyte) ^ ((row & 7) << 4);
}

// ---------------- gate: logits argmax (fp64 accum), 1 wave / token ----------
__global__ __launch_bounds__(256)
void gate_kernel(const float* __restrict__ x, const float* __restrict__ Wg,
                 const float* __restrict__ bg, int* __restrict__ sel) {
  int lane = threadIdx.x & 63;
  int wid  = threadIdx.x >> 6;
  int t = blockIdx.x * 4 + wid;
  if (t >= T_TOK) return;
  const float* xr = x + (size_t)t * DIM;
  double acc[NEXP];
#pragma unroll
  for (int e = 0; e < NEXP; e++) acc[e] = 0.0;
  for (int j = 0; j < DIM / 64; j++) {
    int d = lane + j * 64;
    float xv = xr[d];
    const float4* wr = reinterpret_cast<const float4*>(Wg + (size_t)d * NEXP);
    float4 w0 = wr[0], w1 = wr[1];
    acc[0] += (double)xv * (double)w0.x;
    acc[1] += (double)xv * (double)w0.y;
    acc[2] += (double)xv * (double)w0.z;
    acc[3] += (double)xv * (double)w0.w;
    acc[4] += (double)xv * (double)w1.x;
    acc[5] += (double)xv * (double)w1.y;
    acc[6] += (double)xv * (double)w1.z;
    acc[7] += (double)xv * (double)w1.w;
  }
#pragma unroll
  for (int off = 32; off >= 1; off >>= 1) {
#pragma unroll
    for (int e = 0; e < NEXP; e++) acc[e] += __shfl_down(acc[e], off);
  }
  if (lane == 0) {
    double best = acc[0] + (double)bg[0];
    int bi = 0;
#pragma unroll
    for (int e = 1; e < NEXP; e++) {
      double v = acc[e] + (double)bg[e];
      if (v > best) { best = v; bi = e; }   // strict > : first max wins (jnp.argmax)
    }
    sel[t] = bi;
  }
}

// ---------------- routing bookkeeping ----------------
__global__ void zero_kernel(int* __restrict__ counts) {
  if (threadIdx.x < NEXP) counts[threadIdx.x] = 0;
}

__global__ void hist_kernel(const int* __restrict__ sel, int* __restrict__ counts) {
  __shared__ int lc[NEXP];
  if (threadIdx.x < NEXP) lc[threadIdx.x] = 0;
  __syncthreads();
  int t = blockIdx.x * 256 + threadIdx.x;
  atomicAdd(&lc[sel[t]], 1);
  __syncthreads();
  if (threadIdx.x < NEXP) atomicAdd(&counts[threadIdx.x], lc[threadIdx.x]);
}

__global__ void plan_kernel(const int* __restrict__ counts, int* __restrict__ base,
                            int* __restrict__ cursor, int* __restrict__ tileExpert,
                            int* __restrict__ tilePos, int* __restrict__ tileRows,
                            int* __restrict__ ntiles) {
  if (threadIdx.x == 0) {
    int acc = 0, nt = 0;
    for (int e = 0; e < NEXP; e++) {
      base[e] = acc; cursor[e] = acc;
      int c = counts[e];
      for (int j = 0; j < c; j += BM) {
        tileExpert[nt] = e;
        tilePos[nt]    = acc + j;
        int rem = c - j;
        tileRows[nt]   = rem < BM ? rem : BM;
        nt++;
      }
      acc += c;
    }
    *ntiles = nt;
  }
}

__global__ void scatter_kernel(const int* __restrict__ sel, int* __restrict__ cursor,
                               int* __restrict__ list) {
  __shared__ int lcnt[NEXP];
  __shared__ int lbase[NEXP];
  int tid = threadIdx.x;
  if (tid < NEXP) lcnt[tid] = 0;
  __syncthreads();
  int t = blockIdx.x * 256 + tid;
  int e = sel[t];
  int lpos = atomicAdd(&lcnt[e], 1);
  __syncthreads();
  if (tid < NEXP) lbase[tid] = atomicAdd(&cursor[tid], lcnt[tid]);
  __syncthreads();
  list[lbase[e] + lpos] = t;
}

// ---------------- GEMM1: Hc = gelu(gather(x) @ W1[e] + b1[e]) ----------------
__global__ __launch_bounds__(256)
void gemm1_kernel(const float* __restrict__ x, const float* __restrict__ W1,
                  const float* __restrict__ b1, const int* __restrict__ list,
                  const int* __restrict__ tileExpert, const int* __restrict__ tilePos,
                  const int* __restrict__ tileRows, const int* __restrict__ ntiles,
                  unsigned short* __restrict__ Hc) {
  int tIdx = blockIdx.x;
  if (tIdx >= *ntiles) return;
  int e       = tileExpert[tIdx];
  int posBase = tilePos[tIdx];
  int rows    = tileRows[tIdx];
  int n0      = blockIdx.y * BN;

  __shared__ __align__(16) unsigned char AsB[BM * BK * 2];
  __shared__ __align__(16) unsigned char BsB[BN * BK * 2];

  const int tx   = threadIdx.x;
  const int lane = tx & 63;
  const int wid  = tx >> 6;
  const int wm = wid >> 1, wn = wid & 1;

  // A staging map: 8 float4 units; row = (tx>>4)+16i, k = (tx&15)*4
  const int arow = tx >> 4;
  const int akq  = (tx & 15) << 2;
  int tok[8];
#pragma unroll
  for (int i = 0; i < 8; i++) {
    int r = arow + (i << 4);
    tok[i] = list[posBase + (r < rows ? r : 0)];
  }
  // B staging map: column n = tx&127, k = (tx>>7)*4 + 8i (4 consecutive k packed)
  const int bn  = tx & 127;
  const int bk0 = (tx >> 7) << 2;
  const float* w1e = W1 + (size_t)e * DIM * DHID;

  f32x4 acc[4][4];
#pragma unroll
  for (int mf = 0; mf < 4; mf++)
#pragma unroll
    for (int nf = 0; nf < 4; nf++)
      acc[mf][nf] = f32x4{0.f, 0.f, 0.f, 0.f};

  for (int kt = 0; kt < DIM / BK; kt++) {
    int k0 = kt * BK;
#pragma unroll
    for (int i = 0; i < 8; i++) {       // stage A (gathered x, fp32 -> bf16)
      int r = arow + (i << 4);
      float4 v = *reinterpret_cast<const float4*>(x + (size_t)tok[i] * DIM + (k0 + akq));
      uint2 p; p.x = pack2bf(v.x, v.y); p.y = pack2bf(v.z, v.w);
      *reinterpret_cast<uint2*>(AsB + swz(r, akq << 1)) = p;
    }
#pragma unroll
    for (int i = 0; i < 8; i++) {       // stage B transposed ([n][k])
      int kk = bk0 + (i << 3);
      const float* wp = w1e + (size_t)(k0 + kk) * DHID + (n0 + bn);
      float v0 = wp[0];
      float v1 = wp[DHID];
      float v2 = wp[2 * DHID];
      float v3 = wp[3 * DHID];
      uint2 p; p.x = pack2bf(v0, v1); p.y = pack2bf(v2, v3);
      *reinterpret_cast<uint2*>(BsB + swz(bn, kk << 1)) = p;
    }
    __syncthreads();
#pragma unroll
    for (int ks = 0; ks < 2; ks++) {
      int kbyte = ((ks << 5) + ((lane >> 4) << 3)) << 1;
      bf16x8 af[4], bfv[4];
#pragma unroll
      for (int mf = 0; mf < 4; mf++) {
        int row = (wm << 6) + (mf << 4) + (lane & 15);
        af[mf] = *reinterpret_cast<const bf16x8*>(AsB + swz(row, kbyte));
      }
#pragma unroll
      for (int nf = 0; nf < 4; nf++) {
        int col = (wn << 6) + (nf << 4) + (lane & 15);
        bfv[nf] = *reinterpret_cast<const bf16x8*>(BsB + swz(col, kbyte));
      }
#pragma unroll
      for (int mf = 0; mf < 4; mf++)
#pragma unroll
        for (int nf = 0; nf < 4; nf++)
          acc[mf][nf] = __builtin_amdgcn_mfma_f32_16x16x32_bf16(af[mf], bfv[nf], acc[mf][nf], 0, 0, 0);
    }
    __syncthreads();
  }

  const float* b1e = b1 + (size_t)e * DHID;
#pragma unroll
  for (int nf = 0; nf < 4; nf++) {
    int col = n0 + (wn << 6) + (nf << 4) + (lane & 15);
    float bias = b1e[col];
#pragma unroll
    for (int mf = 0; mf < 4; mf++) {
#pragma unroll
      for (int j = 0; j < 4; j++) {
        int rloc = (wm << 6) + (mf << 4) + ((lane >> 4) << 2) + j;
        if (rloc < rows) {
          float h = acc[mf][nf][j] + bias;
          float g = 0.5f * h * (1.0f + erff(h * 0.70710678118654752f));  // exact gelu
          Hc[(size_t)(posBase + rloc) * DHID + col] = f2bf(g);
        }
      }
    }
  }
}

// ---------------- GEMM2: out = Hc @ W2[e] + b2[e], scatter rows --------------
__global__ __launch_bounds__(256)
void gemm2_kernel(const unsigned short* __restrict__ Hc, const float* __restrict__ W2,
                  const float* __restrict__ b2, const int* __restrict__ list,
                  const int* __restrict__ tileExpert, const int* __restrict__ tilePos,
                  const int* __restrict__ tileRows, const int* __restrict__ ntiles,
                  float* __restrict__ out) {
  int tIdx = blockIdx.x;
  if (tIdx >= *ntiles) return;
  int e       = tileExpert[tIdx];
  int posBase = tilePos[tIdx];
  int rows    = tileRows[tIdx];
  int n0      = blockIdx.y * BN;

  __shared__ __align__(16) unsigned char AsB[BM * BK * 2];
  __shared__ __align__(16) unsigned char BsB[BN * BK * 2];

  const int tx   = threadIdx.x;
  const int lane = tx & 63;
  const int wid  = tx >> 6;
  const int wm = wid >> 1, wn = wid & 1;

  // A staging: 4 chunks of 8 bf16; row = (tx>>3)+32i, k = (tx&7)*8
  const int ar0 = tx >> 3;
  const int akq = (tx & 7) << 3;
  int arowIdx[4];
#pragma unroll
  for (int i = 0; i < 4; i++) {
    int r = ar0 + (i << 5);
    arowIdx[i] = posBase + (r < rows ? r : 0);
  }
  const int bn  = tx & 127;
  const int bk0 = (tx >> 7) << 2;
  const float* w2e = W2 + (size_t)e * DHID * NDOUT;

  f32x4 acc[4][4];
#pragma unroll
  for (int mf = 0; mf < 4; mf++)
#pragma unroll
    for (int nf = 0; nf < 4; nf++)
      acc[mf][nf] = f32x4{0.f, 0.f, 0.f, 0.f};

  for (int kt = 0; kt < DHID / BK; kt++) {
    int k0 = kt * BK;
#pragma unroll
    for (int i = 0; i < 4; i++) {       // stage A (Hc already bf16)
      int r = ar0 + (i << 5);
      int4 v = *reinterpret_cast<const int4*>(Hc + (size_t)arowIdx[i] * DHID + (k0 + akq));
      *reinterpret_cast<int4*>(AsB + swz(r, akq << 1)) = v;
    }
#pragma unroll
    for (int i = 0; i < 8; i++) {       // stage B transposed
      int kk = bk0 + (i << 3);
      const float* wp = w2e + (size_t)(k0 + kk) * NDOUT + (n0 + bn);
      float v0 = wp[0];
      float v1 = wp[NDOUT];
      float v2 = wp[2 * NDOUT];
      float v3 = wp[3 * NDOUT];
      uint2 p; p.x = pack2bf(v0, v1); p.y = pack2bf(v2, v3);
      *reinterpret_cast<uint2*>(BsB + swz(bn, kk << 1)) = p;
    }
    __syncthreads();
#pragma unroll
    for (int ks = 0; ks < 2; ks++) {
      int kbyte = ((ks << 5) + ((lane >> 4) << 3)) << 1;
      bf16x8 af[4], bfv[4];
#pragma unroll
      for (int mf = 0; mf < 4; mf++) {
        int row = (wm << 6) + (mf << 4) + (lane & 15);
        af[mf] = *reinterpret_cast<const bf16x8*>(AsB + swz(row, kbyte));
      }
#pragma unroll
      for (int nf = 0; nf < 4; nf++) {
        int col = (wn << 6) + (nf << 4) + (lane & 15);
        bfv[nf] = *reinterpret_cast<const bf16x8*>(BsB + swz(col, kbyte));
      }
#pragma unroll
      for (int mf = 0; mf < 4; mf++)
#pragma unroll
        for (int nf = 0; nf < 4; nf++)
          acc[mf][nf] = __builtin_amdgcn_mfma_f32_16x16x32_bf16(af[mf], bfv[nf], acc[mf][nf], 0, 0, 0);
    }
    __syncthreads();
  }

  const float* b2e = b2 + (size_t)e * NDOUT;
  int trow[4][4];
#pragma unroll
  for (int mf = 0; mf < 4; mf++)
#pragma unroll
    for (int j = 0; j < 4; j++) {
      int rloc = (wm << 6) + (mf << 4) + ((lane >> 4) << 2) + j;
      trow[mf][j] = (rloc < rows) ? list[posBase + rloc] : -1;
    }
#pragma unroll
  for (int nf = 0; nf < 4; nf++) {
    int col = n0 + (wn << 6) + (nf << 4) + (lane & 15);
    float bias = b2e[col];
#pragma unroll
    for (int mf = 0; mf < 4; mf++)
#pragma unroll
      for (int j = 0; j < 4; j++) {
        int t = trow[mf][j];
        if (t >= 0) out[(size_t)t * NDOUT + col] = acc[mf][nf][j] + bias;
      }
  }
}

// ---------------- launch ----------------
extern "C" void kernel_launch(void* const* d_in, const int* in_sizes, int n_in,
                              void* d_out, int out_size, void* d_ws, size_t ws_size,
                              hipStream_t stream) {
  const float* x  = (const float*)d_in[0];
  const float* Wg = (const float*)d_in[1];
  const float* bg = (const float*)d_in[2];
  const float* W1 = (const float*)d_in[3];
  const float* b1 = (const float*)d_in[4];
  const float* W2 = (const float*)d_in[5];
  const float* b2 = (const float*)d_in[6];
  float* out = (float*)d_out;

  char* ws = (char*)d_ws;
  int* sel        = (int*)(ws);            // 4096 ints
  int* counts     = (int*)(ws + 16384);    // 8
  int* base       = (int*)(ws + 16448);    // 8
  int* cursor     = (int*)(ws + 16512);    // 8
  int* ntiles     = (int*)(ws + 16576);    // 1
  int* tileExpert = (int*)(ws + 16640);    // MAXTILES
  int* tilePos    = (int*)(ws + 16832);    // MAXTILES
  int* tileRows   = (int*)(ws + 17024);    // MAXTILES
  int* list       = (int*)(ws + 17408);    // 4096 ints
  unsigned short* Hc = (unsigned short*)(ws + 65536);  // [T_TOK][DHID] bf16 = 33.5 MB

  gate_kernel<<<T_TOK / 4, 256, 0, stream>>>(x, Wg, bg, sel);
  zero_kernel<<<1, 64, 0, stream>>>(counts);
  hist_kernel<<<T_TOK / 256, 256, 0, stream>>>(sel, counts);
  plan_kernel<<<1, 64, 0, stream>>>(counts, base, cursor, tileExpert, tilePos, tileRows, ntiles);
  scatter_kernel<<<T_TOK / 256, 256, 0, stream>>>(sel, cursor, list);
  gemm1_kernel<<<dim3(MAXTILES, DHID / BN), 256, 0, stream>>>(
      x, W1, b1, list, tileExpert, tilePos, tileRows, ntiles, Hc);
  gemm2_kernel<<<dim3(MAXTILES, NDOUT / BN), 256, 0, stream>>>(
      Hc, W2, b2, list, tileExpert, tilePos, tileRows, ntiles, out);
}

// Round 2
// 320.451 us; speedup vs baseline: 1.0760x; 1.0760x over previous
//
#include <hip/hip_runtime.h>
#include <hip/hip_bf16.h>
#include <math.h>

#define T_TOK 4096
#define DIM   1024
#define NEXP  8
#define DHID  4096
#define NDOUT 1024
#define BM    128
#define BN    128
#define BK    64
#define MAXTILES 40   // sum ceil(c_e/128) <= 32+7

typedef short bf16x8 __attribute__((ext_vector_type(8)));
typedef float f32x4 __attribute__((ext_vector_type(4)));

__device__ __forceinline__ unsigned short f2bf(float f) {
  unsigned u = __float_as_uint(f);
  u += 0x7fffu + ((u >> 16) & 1u);        // RNE
  return (unsigned short)(u >> 16);
}
__device__ __forceinline__ unsigned pack2bf(float a, float b) {
  return (unsigned)f2bf(a) | ((unsigned)f2bf(b) << 16);
}
__device__ __forceinline__ void gl_lds16(const void* g, void* l) {
  __builtin_amdgcn_global_load_lds(
      (const __attribute__((address_space(1))) void*)g,
      (__attribute__((address_space(3))) void*)l, 16, 0, 0);
}

// ---------------- gate: logits argmax (fp64 accum), 1 wave / token ----------
__global__ __launch_bounds__(256)
void gate_kernel(const float* __restrict__ x, const float* __restrict__ Wg,
                 const float* __restrict__ bg, int* __restrict__ sel) {
  int lane = threadIdx.x & 63;
  int wid  = threadIdx.x >> 6;
  int t = blockIdx.x * 4 + wid;
  if (t >= T_TOK) return;
  const float* xr = x + (size_t)t * DIM;
  double acc[NEXP];
#pragma unroll
  for (int e = 0; e < NEXP; e++) acc[e] = 0.0;
  for (int j = 0; j < DIM / 64; j++) {
    int d = lane + j * 64;
    float xv = xr[d];
    const float4* wr = reinterpret_cast<const float4*>(Wg + (size_t)d * NEXP);
    float4 w0 = wr[0], w1 = wr[1];
    acc[0] += (double)xv * (double)w0.x;
    acc[1] += (double)xv * (double)w0.y;
    acc[2] += (double)xv * (double)w0.z;
    acc[3] += (double)xv * (double)w0.w;
    acc[4] += (double)xv * (double)w1.x;
    acc[5] += (double)xv * (double)w1.y;
    acc[6] += (double)xv * (double)w1.z;
    acc[7] += (double)xv * (double)w1.w;
  }
#pragma unroll
  for (int off = 32; off >= 1; off >>= 1) {
#pragma unroll
    for (int e = 0; e < NEXP; e++) acc[e] += __shfl_down(acc[e], off);
  }
  if (lane == 0) {
    double best = acc[0] + (double)bg[0];
    int bi = 0;
#pragma unroll
    for (int e = 1; e < NEXP; e++) {
      double v = acc[e] + (double)bg[e];
      if (v > best) { best = v; bi = e; }   // strict > : first max wins (jnp.argmax)
    }
    sel[t] = bi;
  }
}

// ---------------- routing bookkeeping ----------------
__global__ void zero_kernel(int* __restrict__ counts) {
  if (threadIdx.x < NEXP) counts[threadIdx.x] = 0;
}

__global__ void hist_kernel(const int* __restrict__ sel, int* __restrict__ counts) {
  __shared__ int lc[NEXP];
  if (threadIdx.x < NEXP) lc[threadIdx.x] = 0;
  __syncthreads();
  int t = blockIdx.x * 256 + threadIdx.x;
  atomicAdd(&lc[sel[t]], 1);
  __syncthreads();
  if (threadIdx.x < NEXP) atomicAdd(&counts[threadIdx.x], lc[threadIdx.x]);
}

__global__ void plan_kernel(const int* __restrict__ counts, int* __restrict__ base,
                            int* __restrict__ cursor, int* __restrict__ tileExpert,
                            int* __restrict__ tilePos, int* __restrict__ tileRows,
                            int* __restrict__ ntiles) {
  if (threadIdx.x == 0) {
    int acc = 0, nt = 0;
    for (int e = 0; e < NEXP; e++) {
      base[e] = acc; cursor[e] = acc;
      int c = counts[e];
      for (int j = 0; j < c; j += BM) {
        tileExpert[nt] = e;
        tilePos[nt]    = acc + j;
        int rem = c - j;
        tileRows[nt]   = rem < BM ? rem : BM;
        nt++;
      }
      acc += c;
    }
    *ntiles = nt;
  }
}

__global__ void scatter_kernel(const int* __restrict__ sel, int* __restrict__ cursor,
                               int* __restrict__ list) {
  __shared__ int lcnt[NEXP];
  __shared__ int lbase[NEXP];
  int tid = threadIdx.x;
  if (tid < NEXP) lcnt[tid] = 0;
  __syncthreads();
  int t = blockIdx.x * 256 + tid;
  int e = sel[t];
  int lpos = atomicAdd(&lcnt[e], 1);
  __syncthreads();
  if (tid < NEXP) lbase[tid] = atomicAdd(&cursor[tid], lcnt[tid]);
  __syncthreads();
  list[lbase[e] + lpos] = t;
}

// ---------------- conversions ----------------
__global__ __launch_bounds__(256)
void convert_x_kernel(const float* __restrict__ x, unsigned short* __restrict__ xbf) {
  int i = (blockIdx.x * 256 + threadIdx.x) * 8;
  float4 a = *(const float4*)(x + i);
  float4 b = *(const float4*)(x + i + 4);
  uint4 o;
  o.x = pack2bf(a.x, a.y); o.y = pack2bf(a.z, a.w);
  o.z = pack2bf(b.x, b.y); o.w = pack2bf(b.z, b.w);
  *(uint4*)(xbf + i) = o;
}

// [E][K][N] fp32 -> [E][N][K] bf16, 64x64 tiles via LDS
__global__ __launch_bounds__(256)
void transpose_convert_kernel(const float* __restrict__ in, unsigned short* __restrict__ out,
                              int K, int N) {
  int nb = blockIdx.x, kb = blockIdx.y, e = blockIdx.z;
  const float* inp = in + (size_t)e * K * N;
  unsigned short* outp = out + (size_t)e * N * K;
  __shared__ unsigned short lds[64][72];
  int tx = threadIdx.x;
  int kloc = tx >> 4;            // 0..15
  int n4   = (tx & 15) << 2;     // 0..60
#pragma unroll
  for (int p = 0; p < 4; p++) {
    int k = p * 16 + kloc;
    float4 v = *(const float4*)(inp + (size_t)(kb * 64 + k) * N + nb * 64 + n4);
    lds[n4 + 0][k] = f2bf(v.x);
    lds[n4 + 1][k] = f2bf(v.y);
    lds[n4 + 2][k] = f2bf(v.z);
    lds[n4 + 3][k] = f2bf(v.w);
  }
  __syncthreads();
  int n  = tx >> 2;
  int kq = (tx & 3) << 4;
  uint4 a = *(const uint4*)&lds[n][kq];
  uint4 b = *(const uint4*)&lds[n][kq + 8];
  unsigned short* o = outp + (size_t)(nb * 64 + n) * K + kb * 64 + kq;
  *(uint4*)o = a;
  *(uint4*)(o + 8) = b;
}

// ---------------- GEMM1: Hc = gelu(gather(xbf) @ W1T^T + b1[e]) ----------------
// A: gathered xbf rows, B: W1T [E][DH][DIM] bf16. global_load_lds staging,
// T2 swizzle via pre-swizzled per-lane global source, linear LDS dest.
__global__ __launch_bounds__(256)
void gemm1_kernel(const unsigned short* __restrict__ xbf, const unsigned short* __restrict__ W1T,
                  const float* __restrict__ b1, const int* __restrict__ list,
                  const int* __restrict__ tileExpert, const int* __restrict__ tilePos,
                  const int* __restrict__ tileRows, const int* __restrict__ ntiles,
                  unsigned short* __restrict__ Hc) {
  int tIdx = blockIdx.x;
  if (tIdx >= *ntiles) return;
  int e       = tileExpert[tIdx];
  int posBase = tilePos[tIdx];
  int rows    = tileRows[tIdx];
  int n0      = blockIdx.y * BN;

  __shared__ __align__(1024) unsigned char As[2][BM * 128];
  __shared__ __align__(1024) unsigned char Bs[2][BN * 128];

  const int tx   = threadIdx.x;
  const int lane = tx & 63;
  const int w    = tx >> 6;
  const int wm = w >> 1, wn = w & 1;
  const int u    = lane & 7;
  const int rsub = lane >> 3;
  const int px   = (u ^ rsub) << 4;     // swizzled source 16B-unit offset

  const char* aSrc[4];
  const char* bSrc[4];
#pragma unroll
  for (int l = 0; l < 4; l++) {
    int r = w * 32 + l * 8 + rsub;
    int tok = list[posBase + (r < rows ? r : 0)];
    aSrc[l] = (const char*)xbf + ((size_t)tok * DIM) * 2 + px;
    bSrc[l] = (const char*)W1T + (((size_t)e * DHID + n0 + r) * DIM) * 2 + px;
  }

  f32x4 acc[4][4];
#pragma unroll
  for (int mf = 0; mf < 4; mf++)
#pragma unroll
    for (int nf = 0; nf < 4; nf++)
      acc[mf][nf] = f32x4{0.f, 0.f, 0.f, 0.f};

  const int NT = DIM / BK;   // 16
  auto stage = [&](int buf, int kt) {
    int kb = kt * 128;
#pragma unroll
    for (int l = 0; l < 4; l++) {
      gl_lds16(aSrc[l] + kb, &As[buf][(w * 32 + l * 8) * 128]);
      gl_lds16(bSrc[l] + kb, &Bs[buf][(w * 32 + l * 8) * 128]);
    }
  };
  auto compute = [&](int buf) {
#pragma unroll
    for (int ks = 0; ks < 2; ks++) {
      int kbl = ks * 64 + (lane >> 4) * 16;
      bf16x8 af[4], bv[4];
#pragma unroll
      for (int mf = 0; mf < 4; mf++) {
        int row = (wm << 6) + (mf << 4) + (lane & 15);
        af[mf] = *(const bf16x8*)&As[buf][row * 128 + (kbl ^ ((row & 7) << 4))];
      }
#pragma unroll
      for (int nf = 0; nf < 4; nf++) {
        int row = (wn << 6) + (nf << 4) + (lane & 15);
        bv[nf] = *(const bf16x8*)&Bs[buf][row * 128 + (kbl ^ ((row & 7) << 4))];
      }
#pragma unroll
      for (int mf = 0; mf < 4; mf++)
#pragma unroll
        for (int nf = 0; nf < 4; nf++)
          acc[mf][nf] = __builtin_amdgcn_mfma_f32_16x16x32_bf16(af[mf], bv[nf], acc[mf][nf], 0, 0, 0);
    }
  };

  stage(0, 0);
  __syncthreads();
  int cur = 0;
  for (int kt = 0; kt < NT; kt++) {
    if (kt + 1 < NT) stage(cur ^ 1, kt + 1);
    compute(cur);
    __syncthreads();
    cur ^= 1;
  }

  const float* b1e = b1 + (size_t)e * DHID;
#pragma unroll
  for (int nf = 0; nf < 4; nf++) {
    int col = n0 + (wn << 6) + (nf << 4) + (lane & 15);
    float bias = b1e[col];
#pragma unroll
    for (int mf = 0; mf < 4; mf++) {
#pragma unroll
      for (int j = 0; j < 4; j++) {
        int rloc = (wm << 6) + (mf << 4) + ((lane >> 4) << 2) + j;
        if (rloc < rows) {
          float h = acc[mf][nf][j] + bias;
          float g = 0.5f * h * (1.0f + erff(h * 0.70710678118654752f));  // exact gelu
          Hc[(size_t)(posBase + rloc) * DHID + col] = f2bf(g);
        }
      }
    }
  }
}

// ---------------- GEMM2: out = Hc @ W2T^T + b2[e], scatter rows --------------
__global__ __launch_bounds__(256)
void gemm2_kernel(const unsigned short* __restrict__ Hc, const unsigned short* __restrict__ W2T,
                  const float* __restrict__ b2, const int* __restrict__ list,
                  const int* __restrict__ tileExpert, const int* __restrict__ tilePos,
                  const int* __restrict__ tileRows, const int* __restrict__ ntiles,
                  float* __restrict__ out) {
  int tIdx = blockIdx.x;
  if (tIdx >= *ntiles) return;
  int e       = tileExpert[tIdx];
  int posBase = tilePos[tIdx];
  int rows    = tileRows[tIdx];
  int n0      = blockIdx.y * BN;

  __shared__ __align__(1024) unsigned char As[2][BM * 128];
  __shared__ __align__(1024) unsigned char Bs[2][BN * 128];

  const int tx   = threadIdx.x;
  const int lane = tx & 63;
  const int w    = tx >> 6;
  const int wm = w >> 1, wn = w & 1;
  const int u    = lane & 7;
  const int rsub = lane >> 3;
  const int px   = (u ^ rsub) << 4;

  const char* aSrc[4];
  const char* bSrc[4];
#pragma unroll
  for (int l = 0; l < 4; l++) {
    int r = w * 32 + l * 8 + rsub;
    int ar = posBase + (r < rows ? r : 0);
    aSrc[l] = (const char*)Hc + ((size_t)ar * DHID) * 2 + px;
    bSrc[l] = (const char*)W2T + (((size_t)e * NDOUT + n0 + r) * DHID) * 2 + px;
  }

  f32x4 acc[4][4];
#pragma unroll
  for (int mf = 0; mf < 4; mf++)
#pragma unroll
    for (int nf = 0; nf < 4; nf++)
      acc[mf][nf] = f32x4{0.f, 0.f, 0.f, 0.f};

  const int NT = DHID / BK;   // 64
  auto stage = [&](int buf, int kt) {
    int kb = kt * 128;
#pragma unroll
    for (int l = 0; l < 4; l++) {
      gl_lds16(aSrc[l] + kb, &As[buf][(w * 32 + l * 8) * 128]);
      gl_lds16(bSrc[l] + kb, &Bs[buf][(w * 32 + l * 8) * 128]);
    }
  };
  auto compute = [&](int buf) {
#pragma unroll
    for (int ks = 0; ks < 2; ks++) {
      int kbl = ks * 64 + (lane >> 4) * 16;
      bf16x8 af[4], bv[4];
#pragma unroll
      for (int mf = 0; mf < 4; mf++) {
        int row = (wm << 6) + (mf << 4) + (lane & 15);
        af[mf] = *(const bf16x8*)&As[buf][row * 128 + (kbl ^ ((row & 7) << 4))];
      }
#pragma unroll
      for (int nf = 0; nf < 4; nf++) {
        int row = (wn << 6) + (nf << 4) + (lane & 15);
        bv[nf] = *(const bf16x8*)&Bs[buf][row * 128 + (kbl ^ ((row & 7) << 4))];
      }
#pragma unroll
      for (int mf = 0; mf < 4; mf++)
#pragma unroll
        for (int nf = 0; nf < 4; nf++)
          acc[mf][nf] = __builtin_amdgcn_mfma_f32_16x16x32_bf16(af[mf], bv[nf], acc[mf][nf], 0, 0, 0);
    }
  };

  stage(0, 0);
  __syncthreads();
  int cur = 0;
  for (int kt = 0; kt < NT; kt++) {
    if (kt + 1 < NT) stage(cur ^ 1, kt + 1);
    compute(cur);
    __syncthreads();
    cur ^= 1;
  }

  const float* b2e = b2 + (size_t)e * NDOUT;
  int trow[4][4];
#pragma unroll
  for (int mf = 0; mf < 4; mf++)
#pragma unroll
    for (int j = 0; j < 4; j++) {
      int rloc = (wm << 6) + (mf << 4) + ((lane >> 4) << 2) + j;
      trow[mf][j] = (rloc < rows) ? list[posBase + rloc] : -1;
    }
#pragma unroll
  for (int nf = 0; nf < 4; nf++) {
    int col = n0 + (wn << 6) + (nf << 4) + (lane & 15);
    float bias = b2e[col];
#pragma unroll
    for (int mf = 0; mf < 4; mf++)
#pragma unroll
      for (int j = 0; j < 4; j++) {
        int t = trow[mf][j];
        if (t >= 0) out[(size_t)t * NDOUT + col] = acc[mf][nf][j] + bias;
      }
  }
}

// ---------------- launch ----------------
extern "C" void kernel_launch(void* const* d_in, const int* in_sizes, int n_in,
                              void* d_out, int out_size, void* d_ws, size_t ws_size,
                              hipStream_t stream) {
  const float* x  = (const float*)d_in[0];
  const float* Wg = (const float*)d_in[1];
  const float* bg = (const float*)d_in[2];
  const float* W1 = (const float*)d_in[3];
  const float* b1 = (const float*)d_in[4];
  const float* W2 = (const float*)d_in[5];
  const float* b2 = (const float*)d_in[6];
  float* out = (float*)d_out;

  char* ws = (char*)d_ws;
  int* sel        = (int*)(ws);            // 4096 ints
  int* counts     = (int*)(ws + 16384);    // 8
  int* base       = (int*)(ws + 16448);    // 8
  int* cursor     = (int*)(ws + 16512);    // 8
  int* ntiles     = (int*)(ws + 16576);    // 1
  int* tileExpert = (int*)(ws + 16640);    // MAXTILES
  int* tilePos    = (int*)(ws + 16832);    // MAXTILES
  int* tileRows   = (int*)(ws + 17024);    // MAXTILES
  int* list       = (int*)(ws + 17408);    // 4096 ints

  unsigned short* xbf = (unsigned short*)(ws + (1ull << 20));    // 8 MB
  unsigned short* Hc  = (unsigned short*)(ws + (16ull << 20));   // 32 MB
  unsigned short* W1T = (unsigned short*)(ws + (48ull << 20));   // 64 MB [E][DH][DIM]
  unsigned short* W2T = (unsigned short*)(ws + (112ull << 20));  // 64 MB [E][DOUT][DH]

  gate_kernel<<<T_TOK / 4, 256, 0, stream>>>(x, Wg, bg, sel);
  zero_kernel<<<1, 64, 0, stream>>>(counts);
  hist_kernel<<<T_TOK / 256, 256, 0, stream>>>(sel, counts);
  plan_kernel<<<1, 64, 0, stream>>>(counts, base, cursor, tileExpert, tilePos, tileRows, ntiles);
  scatter_kernel<<<T_TOK / 256, 256, 0, stream>>>(sel, cursor, list);

  convert_x_kernel<<<T_TOK * DIM / (256 * 8), 256, 0, stream>>>(x, xbf);
  transpose_convert_kernel<<<dim3(DHID / 64, DIM / 64, NEXP), 256, 0, stream>>>(W1, W1T, DIM, DHID);
  transpose_convert_kernel<<<dim3(NDOUT / 64, DHID / 64, NEXP), 256, 0, stream>>>(W2, W2T, DHID, NDOUT);

  gemm1_kernel<<<dim3(MAXTILES, DHID / BN), 256, 0, stream>>>(
      xbf, W1T, b1, list, tileExpert, tilePos, tileRows, ntiles, Hc);
  gemm2_kernel<<<dim3(MAXTILES, NDOUT / BN), 256, 0, stream>>>(
      Hc, W2T, b2, list, tileExpert, tilePos, tileRows, ntiles, out);
}

// Round 4
// 289.494 us; speedup vs baseline: 1.1911x; 1.1069x over previous
//
#include <hip/hip_runtime.h>
#include <hip/hip_bf16.h>
#include <math.h>

#define T_TOK 4096
#define DIM   1024
#define NEXP  8
#define DHID  4096
#define NDOUT 1024
#define MAXT2 24    // sum ceil(c_e/256) <= 16+8

typedef short bf16x8 __attribute__((ext_vector_type(8)));
typedef float f32x4 __attribute__((ext_vector_type(4)));

__device__ __forceinline__ unsigned short f2bf(float f) {
  unsigned u = __float_as_uint(f);
  u += 0x7fffu + ((u >> 16) & 1u);        // RNE
  return (unsigned short)(u >> 16);
}
__device__ __forceinline__ unsigned pack2bf(float a, float b) {
  return (unsigned)f2bf(a) | ((unsigned)f2bf(b) << 16);
}
__device__ __forceinline__ void gl_lds16(const void* g, void* l) {
  __builtin_amdgcn_global_load_lds(
      (const __attribute__((address_space(1))) void*)g,
      (__attribute__((address_space(3))) void*)l, 16, 0, 0);
}
#define SBAR()  __builtin_amdgcn_s_barrier()
#define SCHED() __builtin_amdgcn_sched_barrier(0)

// ---------------- gate: logits argmax (fp64 accum), 1 wave / token ----------
__global__ __launch_bounds__(256)
void gate_kernel(const float* __restrict__ x, const float* __restrict__ Wg,
                 const float* __restrict__ bg, int* __restrict__ sel) {
  int lane = threadIdx.x & 63;
  int wid  = threadIdx.x >> 6;
  int t = blockIdx.x * 4 + wid;
  if (t >= T_TOK) return;
  const float* xr = x + (size_t)t * DIM;
  double acc[NEXP];
#pragma unroll
  for (int e = 0; e < NEXP; e++) acc[e] = 0.0;
  for (int j = 0; j < DIM / 64; j++) {
    int d = lane + j * 64;
    float xv = xr[d];
    const float4* wr = reinterpret_cast<const float4*>(Wg + (size_t)d * NEXP);
    float4 w0 = wr[0], w1 = wr[1];
    acc[0] += (double)xv * (double)w0.x;
    acc[1] += (double)xv * (double)w0.y;
    acc[2] += (double)xv * (double)w0.z;
    acc[3] += (double)xv * (double)w0.w;
    acc[4] += (double)xv * (double)w1.x;
    acc[5] += (double)xv * (double)w1.y;
    acc[6] += (double)xv * (double)w1.z;
    acc[7] += (double)xv * (double)w1.w;
  }
#pragma unroll
  for (int off = 32; off >= 1; off >>= 1) {
#pragma unroll
    for (int e = 0; e < NEXP; e++) acc[e] += __shfl_down(acc[e], off);
  }
  if (lane == 0) {
    double best = acc[0] + (double)bg[0];
    int bi = 0;
#pragma unroll
    for (int e = 1; e < NEXP; e++) {
      double v = acc[e] + (double)bg[e];
      if (v > best) { best = v; bi = e; }
    }
    sel[t] = bi;
  }
}

// ---------------- routing bookkeeping ----------------
__global__ void zero_kernel(int* __restrict__ counts) {
  if (threadIdx.x < NEXP) counts[threadIdx.x] = 0;
}

__global__ void hist_kernel(const int* __restrict__ sel, int* __restrict__ counts) {
  __shared__ int lc[NEXP];
  if (threadIdx.x < NEXP) lc[threadIdx.x] = 0;
  __syncthreads();
  int t = blockIdx.x * 256 + threadIdx.x;
  atomicAdd(&lc[sel[t]], 1);
  __syncthreads();
  if (threadIdx.x < NEXP) atomicAdd(&counts[threadIdx.x], lc[threadIdx.x]);
}

__global__ void plan_kernel(const int* __restrict__ counts, int* __restrict__ base,
                            int* __restrict__ cursor, int* __restrict__ tileExpert,
                            int* __restrict__ tilePos, int* __restrict__ tileRows,
                            int* __restrict__ ntiles) {
  if (threadIdx.x == 0) {
    int acc = 0, nt = 0;
    for (int e = 0; e < NEXP; e++) {
      base[e] = acc; cursor[e] = acc;
      int c = counts[e];
      for (int j = 0; j < c; j += 256) {
        tileExpert[nt] = e;
        tilePos[nt]    = acc + j;
        int rem = c - j;
        tileRows[nt]   = rem < 256 ? rem : 256;
        nt++;
      }
      acc += c;
    }
    *ntiles = nt;
  }
}

__global__ void scatter_kernel(const int* __restrict__ sel, int* __restrict__ cursor,
                               int* __restrict__ list) {
  __shared__ int lcnt[NEXP];
  __shared__ int lbase[NEXP];
  int tid = threadIdx.x;
  if (tid < NEXP) lcnt[tid] = 0;
  __syncthreads();
  int t = blockIdx.x * 256 + tid;
  int e = sel[t];
  int lpos = atomicAdd(&lcnt[e], 1);
  __syncthreads();
  if (tid < NEXP) lbase[tid] = atomicAdd(&cursor[tid], lcnt[tid]);
  __syncthreads();
  list[lbase[e] + lpos] = t;
}

// ---------------- conversions ----------------
__global__ __launch_bounds__(256)
void convert_x_kernel(const float* __restrict__ x, unsigned short* __restrict__ xbf) {
  int i = (blockIdx.x * 256 + threadIdx.x) * 8;
  float4 a = *(const float4*)(x + i);
  float4 b = *(const float4*)(x + i + 4);
  uint4 o;
  o.x = pack2bf(a.x, a.y); o.y = pack2bf(a.z, a.w);
  o.z = pack2bf(b.x, b.y); o.w = pack2bf(b.z, b.w);
  *(uint4*)(xbf + i) = o;
}

// [E][K][N] fp32 -> [E][N][K] bf16, 64x64 tiles via LDS
__global__ __launch_bounds__(256)
void transpose_convert_kernel(const float* __restrict__ in, unsigned short* __restrict__ out,
                              int K, int N) {
  int nb = blockIdx.x, kb = blockIdx.y, e = blockIdx.z;
  const float* inp = in + (size_t)e * K * N;
  unsigned short* outp = out + (size_t)e * N * K;
  __shared__ unsigned short lds[64][72];
  int tx = threadIdx.x;
  int kloc = tx >> 4;
  int n4   = (tx & 15) << 2;
#pragma unroll
  for (int p = 0; p < 4; p++) {
    int k = p * 16 + kloc;
    float4 v = *(const float4*)(inp + (size_t)(kb * 64 + k) * N + nb * 64 + n4);
    lds[n4 + 0][k] = f2bf(v.x);
    lds[n4 + 1][k] = f2bf(v.y);
    lds[n4 + 2][k] = f2bf(v.z);
    lds[n4 + 3][k] = f2bf(v.w);
  }
  __syncthreads();
  int n  = tx >> 2;
  int kq = (tx & 3) << 4;
  uint4 a = *(const uint4*)&lds[n][kq];
  uint4 b = *(const uint4*)&lds[n][kq + 8];
  unsigned short* o = outp + (size_t)(nb * 64 + n) * K + kb * 64 + kq;
  *(uint4*)o = a;
  *(uint4*)(o + 8) = b;
}

// ================= 8-phase 256x256 grouped GEMM kernels =================
// BM=BN=256, BK=64, 512 thr = 8 waves (2M x 4N). LDS 128 KiB, T2 swizzle via
// pre-swizzled global source (linear LDS dest). Phases: {RD, STAGE, SBAR,
// MFMA, SBAR}. SYNC INVARIANT: the covering vmcnt for tile T sits at p3 of
// iter T-1, BEFORE that phase's barrier, so every ds_read of tile T is
// issued after a barrier that follows the wait (cross-wave staging visible).
// Counts: prologue 6 STAGEs (12 loads) -> vmcnt(4); steady p3 <=12
// outstanding -> vmcnt(4) drains tile T+1; penult -> vmcnt(0); last -> none.

__global__ __launch_bounds__(512)
void gemm1_kernel(const unsigned short* __restrict__ xbf, const unsigned short* __restrict__ W1T,
                  const float* __restrict__ b1, const int* __restrict__ list,
                  const int* __restrict__ tileExpert, const int* __restrict__ tilePos,
                  const int* __restrict__ tileRows, const int* __restrict__ ntiles,
                  unsigned short* __restrict__ Hc) {
  int tIdx = blockIdx.y;
  if (tIdx >= *ntiles) return;
  int e = tileExpert[tIdx], posBase = tilePos[tIdx], rows = tileRows[tIdx];
  int n0 = blockIdx.x * 256;

  __shared__ __align__(1024) char LDS[131072];

  const int tx = threadIdx.x, lane = tx & 63, w = tx >> 6;
  const int wm = w >> 2, wn = w & 3;
  const int rsub = lane >> 3;
  const int px = ((lane & 7) ^ rsub) << 4;

  const char* aS[2][2];
  const char* bS[2][2];
#pragma unroll
  for (int h = 0; h < 2; h++)
#pragma unroll
    for (int j = 0; j < 2; j++) {
      int rl = w * 16 + j * 8 + rsub;
      int ar = h * 128 + rl; if (ar >= rows) ar = rows - 1;
      int tok = list[posBase + ar];
      aS[h][j] = (const char*)xbf + (size_t)tok * (DIM * 2) + px;
      bS[h][j] = (const char*)W1T + ((size_t)e * DHID + n0 + h * 128 + rl) * (DIM * 2) + px;
    }

  auto STAGE = [&](int buf, int isB, int half, int kt) {
    char* base = &LDS[((buf * 2 + isB) * 2 + half) * 16384 + w * 2048];
    const char* s0 = (isB ? bS[half][0] : aS[half][0]) + kt * 128;
    const char* s1 = (isB ? bS[half][1] : aS[half][1]) + kt * 128;
    gl_lds16(s0, base);
    gl_lds16(s1, base + 1024);
  };

  const int koff0 = ((lane >> 4) * 16) ^ ((lane & 7) << 4);
  const int koff1 = (64 + (lane >> 4) * 16) ^ ((lane & 7) << 4);

  bf16x8 aF[4][2], bF0[2][2], bF1[2][2];
  f32x4 acc[2][2][4][2];
#pragma unroll
  for (int qm = 0; qm < 2; qm++)
#pragma unroll
    for (int qn = 0; qn < 2; qn++)
#pragma unroll
      for (int mf = 0; mf < 4; mf++)
#pragma unroll
        for (int nf = 0; nf < 2; nf++)
          acc[qm][qn][mf][nf] = f32x4{0.f, 0.f, 0.f, 0.f};

  auto RDA = [&](int buf, int qm) {
    const char* Ab = &LDS[((buf * 2 + 0) * 2 + qm) * 16384];
#pragma unroll
    for (int mf = 0; mf < 4; mf++) {
      int ro = (wm * 64 + mf * 16 + (lane & 15)) * 128;
      aF[mf][0] = *(const bf16x8*)(Ab + ro + koff0);
      aF[mf][1] = *(const bf16x8*)(Ab + ro + koff1);
    }
  };
  auto RDB = [&](int buf, int qn, bf16x8 (&bF)[2][2]) {
    const char* Bb = &LDS[((buf * 2 + 1) * 2 + qn) * 16384];
#pragma unroll
    for (int nf = 0; nf < 2; nf++) {
      int ro = (wn * 32 + nf * 16 + (lane & 15)) * 128;
      bF[nf][0] = *(const bf16x8*)(Bb + ro + koff0);
      bF[nf][1] = *(const bf16x8*)(Bb + ro + koff1);
    }
  };
  auto MFMA16 = [&](int qm, int qn, bf16x8 (&bF)[2][2]) {
    __builtin_amdgcn_s_setprio(1);
#pragma unroll
    for (int mf = 0; mf < 4; mf++)
#pragma unroll
      for (int nf = 0; nf < 2; nf++) {
        acc[qm][qn][mf][nf] = __builtin_amdgcn_mfma_f32_16x16x32_bf16(aF[mf][0], bF[nf][0], acc[qm][qn][mf][nf], 0, 0, 0);
        acc[qm][qn][mf][nf] = __builtin_amdgcn_mfma_f32_16x16x32_bf16(aF[mf][1], bF[nf][1], acc[qm][qn][mf][nf], 0, 0, 0);
      }
    __builtin_amdgcn_s_setprio(0);
  };

  const int NTt = DIM / 64;   // 16
  // prologue: tile0 {A0,B0,B1,A1}, tile1 {A0,B0}; wait tile0, publish.
  STAGE(0, 0, 0, 0); STAGE(0, 1, 0, 0); STAGE(0, 1, 1, 0); STAGE(0, 0, 1, 0);
  STAGE(1, 0, 0, 1); STAGE(1, 1, 0, 1);
  asm volatile("s_waitcnt vmcnt(4)" ::: "memory");
  SCHED(); SBAR(); SCHED();

  for (int T = 0; T < NTt; T++) {
    int buf = T & 1, nbuf = buf ^ 1;
    // ---- p0: quadrant (0,0)
    RDA(buf, 0); RDB(buf, 0, bF0);
    if (T + 1 < NTt) STAGE(nbuf, 1, 1, T + 1);
    SCHED(); SBAR(); SCHED();
    MFMA16(0, 0, bF0);
    SCHED(); SBAR(); SCHED();
    // ---- p1: quadrant (0,1)
    RDB(buf, 1, bF1);
    if (T + 1 < NTt) STAGE(nbuf, 0, 1, T + 1);
    SCHED(); SBAR(); SCHED();
    MFMA16(0, 1, bF1);
    SCHED(); SBAR(); SCHED();
    // ---- p2: quadrant (1,1)
    RDA(buf, 1);
    if (T + 2 < NTt) STAGE(buf, 0, 0, T + 2);
    SCHED(); SBAR(); SCHED();
    MFMA16(1, 1, bF1);
    SCHED(); SBAR(); SCHED();
    // ---- p3: quadrant (1,0)  + covering wait for tile T+1
    if (T + 2 < NTt) {
      STAGE(buf, 1, 0, T + 2);
      asm volatile("s_waitcnt vmcnt(4)" ::: "memory");
    } else if (T + 1 < NTt) {
      asm volatile("s_waitcnt vmcnt(0)" ::: "memory");
    }
    SCHED(); SBAR(); SCHED();
    MFMA16(1, 0, bF0);
    SCHED(); SBAR(); SCHED();
  }

  const float* b1e = b1 + (size_t)e * DHID;
#pragma unroll
  for (int qm = 0; qm < 2; qm++)
#pragma unroll
    for (int qn = 0; qn < 2; qn++)
#pragma unroll
      for (int nf = 0; nf < 2; nf++) {
        int col = n0 + qn * 128 + wn * 32 + nf * 16 + (lane & 15);
        float bias = b1e[col];
#pragma unroll
        for (int mf = 0; mf < 4; mf++)
#pragma unroll
          for (int j = 0; j < 4; j++) {
            int rloc = qm * 128 + wm * 64 + mf * 16 + ((lane >> 4) << 2) + j;
            if (rloc < rows) {
              float h = acc[qm][qn][mf][nf][j] + bias;
              float g = 0.5f * h * (1.0f + erff(h * 0.70710678118654752f));
              Hc[(size_t)(posBase + rloc) * DHID + col] = f2bf(g);
            }
          }
      }
}

// GEMM2 split-K (z = 0/1, 32 K-tiles each): packed fp32 partials, bias in split 0.
__global__ __launch_bounds__(512)
void gemm2_kernel(const unsigned short* __restrict__ Hc, const unsigned short* __restrict__ W2T,
                  const float* __restrict__ b2, const int* __restrict__ tileExpert,
                  const int* __restrict__ tilePos, const int* __restrict__ tileRows,
                  const int* __restrict__ ntiles, float* __restrict__ Ppart) {
  int tIdx = blockIdx.y;
  if (tIdx >= *ntiles) return;
  int e = tileExpert[tIdx], posBase = tilePos[tIdx], rows = tileRows[tIdx];
  int n0 = blockIdx.x * 256;
  int zs = blockIdx.z;
  int kt0 = zs * 32;

  __shared__ __align__(1024) char LDS[131072];

  const int tx = threadIdx.x, lane = tx & 63, w = tx >> 6;
  const int wm = w >> 2, wn = w & 3;
  const int rsub = lane >> 3;
  const int px = ((lane & 7) ^ rsub) << 4;

  const char* aS[2][2];
  const char* bS[2][2];
#pragma unroll
  for (int h = 0; h < 2; h++)
#pragma unroll
    for (int j = 0; j < 2; j++) {
      int rl = w * 16 + j * 8 + rsub;
      int ar = h * 128 + rl; if (ar >= rows) ar = rows - 1;
      aS[h][j] = (const char*)Hc + (size_t)(posBase + ar) * (DHID * 2) + (size_t)kt0 * 128 + px;
      bS[h][j] = (const char*)W2T + ((size_t)e * NDOUT + n0 + h * 128 + rl) * (DHID * 2) + (size_t)kt0 * 128 + px;
    }

  auto STAGE = [&](int buf, int isB, int half, int kt) {
    char* base = &LDS[((buf * 2 + isB) * 2 + half) * 16384 + w * 2048];
    const char* s0 = (isB ? bS[half][0] : aS[half][0]) + kt * 128;
    const char* s1 = (isB ? bS[half][1] : aS[half][1]) + kt * 128;
    gl_lds16(s0, base);
    gl_lds16(s1, base + 1024);
  };

  const int koff0 = ((lane >> 4) * 16) ^ ((lane & 7) << 4);
  const int koff1 = (64 + (lane >> 4) * 16) ^ ((lane & 7) << 4);

  bf16x8 aF[4][2], bF0[2][2], bF1[2][2];
  f32x4 acc[2][2][4][2];
#pragma unroll
  for (int qm = 0; qm < 2; qm++)
#pragma unroll
    for (int qn = 0; qn < 2; qn++)
#pragma unroll
      for (int mf = 0; mf < 4; mf++)
#pragma unroll
        for (int nf = 0; nf < 2; nf++)
          acc[qm][qn][mf][nf] = f32x4{0.f, 0.f, 0.f, 0.f};

  auto RDA = [&](int buf, int qm) {
    const char* Ab = &LDS[((buf * 2 + 0) * 2 + qm) * 16384];
#pragma unroll
    for (int mf = 0; mf < 4; mf++) {
      int ro = (wm * 64 + mf * 16 + (lane & 15)) * 128;
      aF[mf][0] = *(const bf16x8*)(Ab + ro + koff0);
      aF[mf][1] = *(const bf16x8*)(Ab + ro + koff1);
    }
  };
  auto RDB = [&](int buf, int qn, bf16x8 (&bF)[2][2]) {
    const char* Bb = &LDS[((buf * 2 + 1) * 2 + qn) * 16384];
#pragma unroll
    for (int nf = 0; nf < 2; nf++) {
      int ro = (wn * 32 + nf * 16 + (lane & 15)) * 128;
      bF[nf][0] = *(const bf16x8*)(Bb + ro + koff0);
      bF[nf][1] = *(const bf16x8*)(Bb + ro + koff1);
    }
  };
  auto MFMA16 = [&](int qm, int qn, bf16x8 (&bF)[2][2]) {
    __builtin_amdgcn_s_setprio(1);
#pragma unroll
    for (int mf = 0; mf < 4; mf++)
#pragma unroll
      for (int nf = 0; nf < 2; nf++) {
        acc[qm][qn][mf][nf] = __builtin_amdgcn_mfma_f32_16x16x32_bf16(aF[mf][0], bF[nf][0], acc[qm][qn][mf][nf], 0, 0, 0);
        acc[qm][qn][mf][nf] = __builtin_amdgcn_mfma_f32_16x16x32_bf16(aF[mf][1], bF[nf][1], acc[qm][qn][mf][nf], 0, 0, 0);
      }
    __builtin_amdgcn_s_setprio(0);
  };

  const int NTt = 32;
  STAGE(0, 0, 0, 0); STAGE(0, 1, 0, 0); STAGE(0, 1, 1, 0); STAGE(0, 0, 1, 0);
  STAGE(1, 0, 0, 1); STAGE(1, 1, 0, 1);
  asm volatile("s_waitcnt vmcnt(4)" ::: "memory");
  SCHED(); SBAR(); SCHED();

  for (int T = 0; T < NTt; T++) {
    int buf = T & 1, nbuf = buf ^ 1;
    RDA(buf, 0); RDB(buf, 0, bF0);
    if (T + 1 < NTt) STAGE(nbuf, 1, 1, T + 1);
    SCHED(); SBAR(); SCHED();
    MFMA16(0, 0, bF0);
    SCHED(); SBAR(); SCHED();
    RDB(buf, 1, bF1);
    if (T + 1 < NTt) STAGE(nbuf, 0, 1, T + 1);
    SCHED(); SBAR(); SCHED();
    MFMA16(0, 1, bF1);
    SCHED(); SBAR(); SCHED();
    RDA(buf, 1);
    if (T + 2 < NTt) STAGE(buf, 0, 0, T + 2);
    SCHED(); SBAR(); SCHED();
    MFMA16(1, 1, bF1);
    SCHED(); SBAR(); SCHED();
    if (T + 2 < NTt) {
      STAGE(buf, 1, 0, T + 2);
      asm volatile("s_waitcnt vmcnt(4)" ::: "memory");
    } else if (T + 1 < NTt) {
      asm volatile("s_waitcnt vmcnt(0)" ::: "memory");
    }
    SCHED(); SBAR(); SCHED();
    MFMA16(1, 0, bF0);
    SCHED(); SBAR(); SCHED();
  }

  const float* b2e = b2 + (size_t)e * NDOUT;
  float* P = Ppart + (size_t)zs * T_TOK * NDOUT;
#pragma unroll
  for (int qm = 0; qm < 2; qm++)
#pragma unroll
    for (int qn = 0; qn < 2; qn++)
#pragma unroll
      for (int nf = 0; nf < 2; nf++) {
        int col = n0 + qn * 128 + wn * 32 + nf * 16 + (lane & 15);
        float bias = (zs == 0) ? b2e[col] : 0.f;
#pragma unroll
        for (int mf = 0; mf < 4; mf++)
#pragma unroll
          for (int j = 0; j < 4; j++) {
            int rloc = qm * 128 + wm * 64 + mf * 16 + ((lane >> 4) << 2) + j;
            if (rloc < rows)
              P[(size_t)(posBase + rloc) * NDOUT + col] = acc[qm][qn][mf][nf][j] + bias;
          }
      }
}

// out[list[pos]] = P0[pos] + P1[pos]   (bias already in P0)
__global__ __launch_bounds__(256)
void reduce_kernel(const float* __restrict__ Ppart, const int* __restrict__ list,
                   float* __restrict__ out) {
  int pos = blockIdx.x;
  int tok = list[pos];
  int c = threadIdx.x * 4;
  float4 a = *(const float4*)(Ppart + (size_t)pos * NDOUT + c);
  float4 b = *(const float4*)(Ppart + (size_t)T_TOK * NDOUT + (size_t)pos * NDOUT + c);
  float4 o; o.x = a.x + b.x; o.y = a.y + b.y; o.z = a.z + b.z; o.w = a.w + b.w;
  *(float4*)(out + (size_t)tok * NDOUT + c) = o;
}

// ---------------- launch ----------------
extern "C" void kernel_launch(void* const* d_in, const int* in_sizes, int n_in,
                              void* d_out, int out_size, void* d_ws, size_t ws_size,
                              hipStream_t stream) {
  const float* x  = (const float*)d_in[0];
  const float* Wg = (const float*)d_in[1];
  const float* bg = (const float*)d_in[2];
  const float* W1 = (const float*)d_in[3];
  const float* b1 = (const float*)d_in[4];
  const float* W2 = (const float*)d_in[5];
  const float* b2 = (const float*)d_in[6];
  float* out = (float*)d_out;

  char* ws = (char*)d_ws;
  int* sel        = (int*)(ws);
  int* counts     = (int*)(ws + 16384);
  int* base       = (int*)(ws + 16448);
  int* cursor     = (int*)(ws + 16512);
  int* ntiles     = (int*)(ws + 16576);
  int* tileExpert = (int*)(ws + 16640);
  int* tilePos    = (int*)(ws + 16832);
  int* tileRows   = (int*)(ws + 17024);
  int* list       = (int*)(ws + 17408);

  unsigned short* xbf = (unsigned short*)(ws + (1ull << 20));    // 8 MB
  unsigned short* Hc  = (unsigned short*)(ws + (16ull << 20));   // 32 MB
  unsigned short* W1T = (unsigned short*)(ws + (48ull << 20));   // 64 MB [E][DH][DIM]
  unsigned short* W2T = (unsigned short*)(ws + (112ull << 20));  // 64 MB [E][DOUT][DH]
  float* Ppart        = (float*)(ws + (48ull << 20));            // reuse W1T region after gemm1 (34 MB)

  gate_kernel<<<T_TOK / 4, 256, 0, stream>>>(x, Wg, bg, sel);
  zero_kernel<<<1, 64, 0, stream>>>(counts);
  hist_kernel<<<T_TOK / 256, 256, 0, stream>>>(sel, counts);
  plan_kernel<<<1, 64, 0, stream>>>(counts, base, cursor, tileExpert, tilePos, tileRows, ntiles);
  scatter_kernel<<<T_TOK / 256, 256, 0, stream>>>(sel, cursor, list);

  convert_x_kernel<<<T_TOK * DIM / (256 * 8), 256, 0, stream>>>(x, xbf);
  transpose_convert_kernel<<<dim3(DHID / 64, DIM / 64, NEXP), 256, 0, stream>>>(W1, W1T, DIM, DHID);
  transpose_convert_kernel<<<dim3(NDOUT / 64, DHID / 64, NEXP), 256, 0, stream>>>(W2, W2T, DHID, NDOUT);

  gemm1_kernel<<<dim3(DHID / 256, MAXT2), 512, 0, stream>>>(
      xbf, W1T, b1, list, tileExpert, tilePos, tileRows, ntiles, Hc);
  gemm2_kernel<<<dim3(NDOUT / 256, MAXT2, 2), 512, 0, stream>>>(
      Hc, W2T, b2, tileExpert, tilePos, tileRows, ntiles, Ppart);
  reduce_kernel<<<T_TOK, 256, 0, stream>>>(Ppart, list, out);
}